// Round 11
// baseline (566.661 us; speedup 1.0000x reference)
//
#include <hip/hip_runtime.h>
#include <hip/hip_bf16.h>

typedef unsigned short u16;
typedef unsigned int   u32;
typedef short bf16x8 __attribute__((ext_vector_type(8)));
typedef short bf16x4 __attribute__((ext_vector_type(4)));
typedef float f32x4  __attribute__((ext_vector_type(4)));

#define EPS 1e-5f

// ws layout (u16 units)
#define W2B_OFF 0
#define W1B_OFF 55296
#define FCW_OFF (55296 + 4096)

__device__ __forceinline__ u16 f2bf(float f) {
    __hip_bfloat16 h = __float2bfloat16(f);
    return *(const u16*)&h;
}
__device__ __forceinline__ float bfu_lo(u32 u) {
    union { u32 i; float f; } v; v.i = u << 16; return v.f;
}
__device__ __forceinline__ float bfu_hi(u32 u) {
    union { u32 i; float f; } v; v.i = u & 0xffff0000u; return v.f;
}

union BV { bf16x8 v; bf16x4 h[2]; };

// ---- prep: pack weights to bf16 (normal launch, stream-ordered) ----
__global__ __launch_bounds__(256) void prep_kernel(
        const float* __restrict__ W2, const float* __restrict__ W1,
        const float* __restrict__ fcw1, u16* __restrict__ ws) {
    int i = blockIdx.x * 256 + threadIdx.x;
    if (i < 55296) {           // w2b [tap][cout][ci]
        int tap = i >> 11, rem = i & 2047;
        int co = rem >> 5, ci = rem & 31;
        ws[W2B_OFF + i] = f2bf(W2[(size_t)tap * 2048 + ci * 64 + co]);
    }
    if (i < 4096) {            // w1b [ks][quad][cout][8]; tap>=27 zero
        int j = i & 7, cout = (i >> 3) & 31, quad = (i >> 8) & 3, ks = i >> 10;
        int tap = ks * 8 + quad * 2 + (j >> 2), ci = j & 3;
        ws[W1B_OFF + i] = (tap < 27) ? f2bf(W1[tap * 128 + ci * 32 + cout]) : (u16)0;
    }
    if (i < 65536)             // fcw1b [j][k]
        ws[FCW_OFF + i] = f2bf(fcw1[i]);
}

// ---- mono kernel: grid 2048 x 256, 2 items per block ----
// Per item: conv1 MFMA (in-register 2x2x2 pool) -> conv2 MFMA (wave = cout
// tile) -> pooled f32 to LDS h2[it]. Then block-local FC (VALU dot): item =
// t>>7, neuron j = t&127. No global intermediates, no cooperative launch.
__global__ __launch_bounds__(256, 4) void mono_kernel(
        const float* __restrict__ x,    const u32*  __restrict__ mask,
        const float* __restrict__ g1,   const float* __restrict__ b1,
        const float* __restrict__ m1,   const float* __restrict__ v1,
        const float* __restrict__ g2,   const float* __restrict__ b2,
        const float* __restrict__ m2,   const float* __restrict__ v2,
        const float* __restrict__ fcb1, const float* __restrict__ fcw2,
        const float* __restrict__ fcb2, const u16* __restrict__ ws,
        float* __restrict__ out) {

    const u16* w2b   = ws + W2B_OFF;
    const u16* w1b   = ws + W1B_OFF;
    const u16* fcw1b = ws + FCW_OFF;

    __shared__ __align__(16) u16 xb[513 * 4];     // [site+zero][ci(4)]
    __shared__ int   msk[512];
    __shared__ __align__(16) u16 act16[65 * 40];  // [ps+zero][ci(32)+pad]
    __shared__ float mf2s[64];
    __shared__ float h2[2][512];                  // pooled conv2 out per item
    __shared__ float sc1s[32], sh1s[32], sc2s[64], sh2s[64];
    __shared__ float red[4];

    const int blk = blockIdx.x;
    const int t   = threadIdx.x;

    if (t < 32) {
        float sc = g1[t] / sqrtf(v1[t] + EPS);
        sc1s[t] = sc; sh1s[t] = b1[t] - m1[t] * sc;
    } else if (t < 96) {
        int c = t - 32;
        float sc = g2[c] / sqrtf(v2[c] + EPS);
        sc2s[c] = sc; sh2s[c] = b2[c] - m2[c] * sc;
    }
    if (t < 2)  ((u32*)xb)[1024 + t] = 0u;          // zero site row 512
    if (t < 20) ((u32*)act16)[64 * 20 + t] = 0u;    // zero ps row 64

    const int lane = t & 63;
    const int n    = lane & 15;
    const int quad = lane >> 4;
    const int w    = __builtin_amdgcn_readfirstlane(t >> 6);

    // conv1 A-frags + per-lane tap tables (shared across items)
    bf16x8 afr[4][2];
    #pragma unroll
    for (int ks = 0; ks < 4; ++ks)
        #pragma unroll
        for (int mt = 0; mt < 2; ++mt)
            afr[ks][mt] = *(const bf16x8*)(w1b +
                (((ks * 4 + quad) * 32) + mt * 16 + n) * 8);

    int kdm1_[8], khm1_[8], kwm1_[8];
    #pragma unroll
    for (int q = 0; q < 8; ++q) {
        int tap = (q >> 1) * 8 + quad * 2 + (q & 1);
        bool tv = tap < 27;
        int tc = tv ? tap : 26;
        int kd = tc / 9, rr = tc - kd * 9, kh = rr / 3, kw = rr - kh * 3;
        kdm1_[q] = kd - 1; khm1_[q] = kh - 1; kwm1_[q] = tv ? (kw - 1) : 100;
    }

    // ---- per-item conv pipeline ----
    #pragma unroll 1
    for (int it = 0; it < 2; ++it) {
        const int b = blk * 2 + it;
        __syncthreads();   // prior item's LDS readers done before restage

        {   // stage x -> bf16 [site][ci]; mask
            const float* xp = x + (size_t)b * 2048;
            const u32*   mp = mask + (size_t)b * 512;
            for (int s = t; s < 512; s += 256) {
                float a0 = xp[s], a1 = xp[512 + s], a2 = xp[1024 + s], a3 = xp[1536 + s];
                ((u32*)xb)[s * 2]     = (u32)f2bf(a0) | ((u32)f2bf(a1) << 16);
                ((u32*)xb)[s * 2 + 1] = (u32)f2bf(a2) | ((u32)f2bf(a3) << 16);
                msk[s] = (mp[s] != 0u);
            }
        }
        __syncthreads();

        // conv1(4->32) MFMA + in-register 2x2x2 maxpool (r9-validated)
        {
            const int py_ = n >> 2, px_ = n & 3;   // pooled coords; pz = w
            float pmax[8];
            #pragma unroll
            for (int j = 0; j < 8; ++j) pmax[j] = 0.f;
            int any = 0;

            #pragma unroll
            for (int i = 0; i < 8; ++i) {
                const int z  = 2 * w   + (i >> 2);
                const int y  = 2 * py_ + ((i >> 1) & 1);
                const int xx = 2 * px_ + (i & 1);
                const int s  = z * 64 + y * 8 + xx;

                f32x4 acc0 = (f32x4){0.f, 0.f, 0.f, 0.f};
                f32x4 acc1 = (f32x4){0.f, 0.f, 0.f, 0.f};

                #pragma unroll
                for (int ks = 0; ks < 4; ++ks) {
                    int qA = ks * 2, qB = qA + 1;
                    int zzA = z + kdm1_[qA], yyA = y + khm1_[qA], xnA = xx + kwm1_[qA];
                    int zzB = z + kdm1_[qB], yyB = y + khm1_[qB], xnB = xx + kwm1_[qB];
                    bool vA = ((unsigned)zzA < 8u) && ((unsigned)yyA < 8u) && ((unsigned)xnA < 8u);
                    bool vB = ((unsigned)zzB < 8u) && ((unsigned)yyB < 8u) && ((unsigned)xnB < 8u);
                    int rA = vA ? (zzA * 64 + yyA * 8 + xnA) : 512;
                    int rB = vB ? (zzB * 64 + yyB * 8 + xnB) : 512;
                    BV bv;
                    bv.h[0] = *(const bf16x4*)(xb + rA * 4);
                    bv.h[1] = *(const bf16x4*)(xb + rB * 4);
                    acc0 = __builtin_amdgcn_mfma_f32_16x16x32_bf16(afr[ks][0], bv.v, acc0, 0, 0, 0);
                    acc1 = __builtin_amdgcn_mfma_f32_16x16x32_bf16(afr[ks][1], bv.v, acc1, 0, 0, 0);
                }

                const int mbit = msk[s];
                const float mk = mbit ? 1.f : 0.f;
                any |= mbit;
                #pragma unroll
                for (int r = 0; r < 4; ++r) {
                    int c0 = quad * 4 + r, c1 = 16 + quad * 4 + r;
                    pmax[r]     = fmaxf(pmax[r],     fmaxf(acc0[r] * sc1s[c0] + sh1s[c0], 0.f) * mk);
                    pmax[4 + r] = fmaxf(pmax[4 + r], fmaxf(acc1[r] * sc1s[c1] + sh1s[c1], 0.f) * mk);
                }
            }

            const int ps = w * 16 + n;
            #pragma unroll
            for (int mt = 0; mt < 2; ++mt) {
                u32 lo = (u32)f2bf(pmax[mt * 4])     | ((u32)f2bf(pmax[mt * 4 + 1]) << 16);
                u32 hi = (u32)f2bf(pmax[mt * 4 + 2]) | ((u32)f2bf(pmax[mt * 4 + 3]) << 16);
                ((u32*)act16)[ps * 20 + mt * 8 + quad * 2]     = lo;
                ((u32*)act16)[ps * 20 + mt * 8 + quad * 2 + 1] = hi;
            }
            if (quad == 0) mf2s[ps] = any ? 1.f : 0.f;
        }
        __syncthreads();

        // conv2(32->64): wave = cout tile; pooled f32 -> h2[it] (r9-validated)
        {
            f32x4 acc[4];
            #pragma unroll
            for (int g = 0; g < 4; ++g) acc[g] = (f32x4){0.f, 0.f, 0.f, 0.f};

            #pragma unroll
            for (int kd = 0; kd < 3; ++kd) {
                #pragma unroll
                for (int kh = 0; kh < 3; ++kh) {
                    int yy = (n >> 2) + kh - 1; bool vy = (unsigned)yy < 4u;
                    #pragma unroll
                    for (int kw = 0; kw < 3; ++kw) {
                        int xn = (n & 3) + kw - 1; bool vyx = vy && ((unsigned)xn < 4u);
                        const int dyx = (kh - 1) * 4 + (kw - 1);
                        const int tap = (kd * 3 + kh) * 3 + kw;
                        bf16x8 afrag = *(const bf16x8*)(w2b + tap * 2048 + (w * 16 + n) * 32 + quad * 8);
                        #pragma unroll
                        for (int g = 0; g < 4; ++g) {
                            const int gp = g + kd - 1;
                            if (gp < 0 || gp > 3) continue;   // compile-time pruned
                            int row = vyx ? (gp * 16 + n + dyx) : 64;
                            bf16x8 bfrag = *(const bf16x8*)(act16 + row * 40 + quad * 8);
                            acc[g] = __builtin_amdgcn_mfma_f32_16x16x32_bf16(
                                         afrag, bfrag, acc[g], 0, 0, 0);
                        }
                    }
                }
            }

            #pragma unroll
            for (int r = 0; r < 4; ++r) {
                const int cout = w * 16 + quad * 4 + r;
                float p2g[4];
                #pragma unroll
                for (int g = 0; g < 4; ++g) {
                    const int site = g * 16 + n;
                    float val = fmaxf(acc[g][r] * sc2s[cout] + sh2s[cout], 0.f) * mf2s[site];
                    float p1 = fmaxf(val, __shfl_xor(val, 1, 64));
                    p2g[g]   = fmaxf(p1,  __shfl_xor(p1, 4, 64));
                }
                if ((n & 5) == 0) {
                    const int py = (n >> 3) & 1, px = (n >> 1) & 1;
                    h2[it][cout * 8 + 0 + py * 2 + px] = fmaxf(p2g[0], p2g[1]);
                    h2[it][cout * 8 + 4 + py * 2 + px] = fmaxf(p2g[2], p2g[3]);
                }
            }
        }
    }
    __syncthreads();

    // ---- FC for the block's 2 items: item = t>>7, neuron j = t&127 ----
    {
        const int item = t >> 7;
        const int j    = t & 127;
        float acc = fcb1[j];
        const uint4* wrow = (const uint4*)(fcw1b + (size_t)j * 512);
        const float* hp0  = h2[item];
        #pragma unroll 4
        for (int kb = 0; kb < 64; ++kb) {
            uint4 wv = wrow[kb];
            const float* hp = hp0 + kb * 8;
            acc += hp[0] * bfu_lo(wv.x) + hp[1] * bfu_hi(wv.x)
                 + hp[2] * bfu_lo(wv.y) + hp[3] * bfu_hi(wv.y)
                 + hp[4] * bfu_lo(wv.z) + hp[5] * bfu_hi(wv.z)
                 + hp[6] * bfu_lo(wv.w) + hp[7] * bfu_hi(wv.w);
        }
        float a = (acc >= 0.f) ? acc : 0.01f * acc;   // LeakyReLU
        float p = a * fcw2[j];
        #pragma unroll
        for (int off = 32; off > 0; off >>= 1) p += __shfl_down(p, off, 64);
        if (lane == 0) red[w] = p;                    // wave partial
        __syncthreads();
        if (t < 2)
            out[blk * 2 + t] = red[t * 2] + red[t * 2 + 1] + fcb2[0];
    }
}

extern "C" void kernel_launch(void* const* d_in, const int* in_sizes, int n_in,
                              void* d_out, int out_size, void* d_ws, size_t ws_size,
                              hipStream_t stream) {
    const float* x    = (const float*)d_in[0];
    const u32*   mask = (const u32*)d_in[1];
    const float* W1   = (const float*)d_in[2];
    const float* g1   = (const float*)d_in[3];
    const float* b1   = (const float*)d_in[4];
    const float* m1   = (const float*)d_in[5];
    const float* v1   = (const float*)d_in[6];
    const float* W2   = (const float*)d_in[7];
    const float* g2   = (const float*)d_in[8];
    const float* b2   = (const float*)d_in[9];
    const float* m2   = (const float*)d_in[10];
    const float* v2   = (const float*)d_in[11];
    const float* fcw1 = (const float*)d_in[12];
    const float* fcb1 = (const float*)d_in[13];
    const float* fcw2 = (const float*)d_in[14];
    const float* fcb2 = (const float*)d_in[15];
    u16*   ws  = (u16*)d_ws;           // ~250 KB used
    float* out = (float*)d_out;

    prep_kernel<<<256, 256, 0, stream>>>(W2, W1, fcw1, ws);
    mono_kernel<<<2048, 256, 0, stream>>>(
        x, mask, g1, b1, m1, v1, g2, b2, m2, v2,
        fcb1, fcw2, fcb2, ws, out);
}

// Round 12
// 270.003 us; speedup vs baseline: 2.0987x; 2.0987x over previous
//
#include <hip/hip_runtime.h>
#include <hip/hip_bf16.h>

typedef unsigned short u16;
typedef unsigned int   u32;
typedef short bf16x8 __attribute__((ext_vector_type(8)));
typedef short bf16x4 __attribute__((ext_vector_type(4)));
typedef float f32x4  __attribute__((ext_vector_type(4)));

#define EPS 1e-5f

// ws layout (u16 units)
#define W2B_OFF 0
#define W1B_OFF 55296
#define FCW_OFF (55296 + 4096)

__device__ __forceinline__ u16 f2bf(float f) {
    __hip_bfloat16 h = __float2bfloat16(f);
    return *(const u16*)&h;
}
__device__ __forceinline__ float bfu_lo(u32 u) {
    union { u32 i; float f; } v; v.i = u << 16; return v.f;
}
__device__ __forceinline__ float bfu_hi(u32 u) {
    union { u32 i; float f; } v; v.i = u & 0xffff0000u; return v.f;
}

union BV { bf16x8 v; bf16x4 h[2]; };

// ---- prep: pack weights to bf16 (normal launch, stream-ordered) ----
__global__ __launch_bounds__(256) void prep_kernel(
        const float* __restrict__ W2, const float* __restrict__ W1,
        const float* __restrict__ fcw1, u16* __restrict__ ws) {
    int i = blockIdx.x * 256 + threadIdx.x;
    if (i < 55296) {           // w2b [tap][cout][ci]
        int tap = i >> 11, rem = i & 2047;
        int co = rem >> 5, ci = rem & 31;
        ws[W2B_OFF + i] = f2bf(W2[(size_t)tap * 2048 + ci * 64 + co]);
    }
    if (i < 4096) {            // w1b [ks][quad][cout][8]; tap>=27 zero
        int j = i & 7, cout = (i >> 3) & 31, quad = (i >> 8) & 3, ks = i >> 10;
        int tap = ks * 8 + quad * 2 + (j >> 2), ci = j & 3;
        ws[W1B_OFF + i] = (tap < 27) ? f2bf(W1[tap * 128 + ci * 32 + cout]) : (u16)0;
    }
    if (i < 65536)             // fcw1b [j][k]
        ws[FCW_OFF + i] = f2bf(fcw1[i]);
}

// ---- mono kernel: grid 2048 x 256, 2 items per block ----
// NOTE: plain __launch_bounds__(256). Round 11's (256,4) capped the register
// budget and caused ~1.1 GB of scratch spill traffic (FETCH+WRITE ~563 MB
// each) — 3x slowdown. Do not re-add an occupancy bound here.
__global__ __launch_bounds__(256) void mono_kernel(
        const float* __restrict__ x,    const u32*  __restrict__ mask,
        const float* __restrict__ g1,   const float* __restrict__ b1,
        const float* __restrict__ m1,   const float* __restrict__ v1,
        const float* __restrict__ g2,   const float* __restrict__ b2,
        const float* __restrict__ m2,   const float* __restrict__ v2,
        const float* __restrict__ fcb1, const float* __restrict__ fcw2,
        const float* __restrict__ fcb2, const u16* __restrict__ ws,
        float* __restrict__ out) {

    const u16* w2b   = ws + W2B_OFF;
    const u16* w1b   = ws + W1B_OFF;
    const u16* fcw1b = ws + FCW_OFF;

    __shared__ __align__(16) u16 xb[513 * 4];     // [site+zero][ci(4)]
    __shared__ int   msk[512];
    __shared__ __align__(16) u16 act16[65 * 40];  // [ps+zero][ci(32)+pad]
    __shared__ float mf2s[64];
    __shared__ float h2[2][512];                  // pooled conv2 out per item
    __shared__ float sc1s[32], sh1s[32], sc2s[64], sh2s[64];
    __shared__ float red[4];

    const int blk = blockIdx.x;
    const int t   = threadIdx.x;

    if (t < 32) {
        float sc = g1[t] / sqrtf(v1[t] + EPS);
        sc1s[t] = sc; sh1s[t] = b1[t] - m1[t] * sc;
    } else if (t < 96) {
        int c = t - 32;
        float sc = g2[c] / sqrtf(v2[c] + EPS);
        sc2s[c] = sc; sh2s[c] = b2[c] - m2[c] * sc;
    }
    if (t < 2)  ((u32*)xb)[1024 + t] = 0u;          // zero site row 512
    if (t < 20) ((u32*)act16)[64 * 20 + t] = 0u;    // zero ps row 64

    const int lane = t & 63;
    const int n    = lane & 15;
    const int quad = lane >> 4;
    const int w    = __builtin_amdgcn_readfirstlane(t >> 6);

    // conv1 A-frags + per-lane tap tables (shared across items)
    bf16x8 afr[4][2];
    #pragma unroll
    for (int ks = 0; ks < 4; ++ks)
        #pragma unroll
        for (int mt = 0; mt < 2; ++mt)
            afr[ks][mt] = *(const bf16x8*)(w1b +
                (((ks * 4 + quad) * 32) + mt * 16 + n) * 8);

    int kdm1_[8], khm1_[8], kwm1_[8];
    #pragma unroll
    for (int q = 0; q < 8; ++q) {
        int tap = (q >> 1) * 8 + quad * 2 + (q & 1);
        bool tv = tap < 27;
        int tc = tv ? tap : 26;
        int kd = tc / 9, rr = tc - kd * 9, kh = rr / 3, kw = rr - kh * 3;
        kdm1_[q] = kd - 1; khm1_[q] = kh - 1; kwm1_[q] = tv ? (kw - 1) : 100;
    }

    // ---- per-item conv pipeline ----
    #pragma unroll 1
    for (int it = 0; it < 2; ++it) {
        const int b = blk * 2 + it;
        __syncthreads();   // prior item's LDS readers done before restage

        {   // stage x -> bf16 [site][ci]; mask
            const float* xp = x + (size_t)b * 2048;
            const u32*   mp = mask + (size_t)b * 512;
            for (int s = t; s < 512; s += 256) {
                float a0 = xp[s], a1 = xp[512 + s], a2 = xp[1024 + s], a3 = xp[1536 + s];
                ((u32*)xb)[s * 2]     = (u32)f2bf(a0) | ((u32)f2bf(a1) << 16);
                ((u32*)xb)[s * 2 + 1] = (u32)f2bf(a2) | ((u32)f2bf(a3) << 16);
                msk[s] = (mp[s] != 0u);
            }
        }
        __syncthreads();

        // conv1(4->32) MFMA + in-register 2x2x2 maxpool (r9-validated)
        {
            const int py_ = n >> 2, px_ = n & 3;   // pooled coords; pz = w
            float pmax[8];
            #pragma unroll
            for (int j = 0; j < 8; ++j) pmax[j] = 0.f;
            int any = 0;

            #pragma unroll
            for (int i = 0; i < 8; ++i) {
                const int z  = 2 * w   + (i >> 2);
                const int y  = 2 * py_ + ((i >> 1) & 1);
                const int xx = 2 * px_ + (i & 1);
                const int s  = z * 64 + y * 8 + xx;

                f32x4 acc0 = (f32x4){0.f, 0.f, 0.f, 0.f};
                f32x4 acc1 = (f32x4){0.f, 0.f, 0.f, 0.f};

                #pragma unroll
                for (int ks = 0; ks < 4; ++ks) {
                    int qA = ks * 2, qB = qA + 1;
                    int zzA = z + kdm1_[qA], yyA = y + khm1_[qA], xnA = xx + kwm1_[qA];
                    int zzB = z + kdm1_[qB], yyB = y + khm1_[qB], xnB = xx + kwm1_[qB];
                    bool vA = ((unsigned)zzA < 8u) && ((unsigned)yyA < 8u) && ((unsigned)xnA < 8u);
                    bool vB = ((unsigned)zzB < 8u) && ((unsigned)yyB < 8u) && ((unsigned)xnB < 8u);
                    int rA = vA ? (zzA * 64 + yyA * 8 + xnA) : 512;
                    int rB = vB ? (zzB * 64 + yyB * 8 + xnB) : 512;
                    BV bv;
                    bv.h[0] = *(const bf16x4*)(xb + rA * 4);
                    bv.h[1] = *(const bf16x4*)(xb + rB * 4);
                    acc0 = __builtin_amdgcn_mfma_f32_16x16x32_bf16(afr[ks][0], bv.v, acc0, 0, 0, 0);
                    acc1 = __builtin_amdgcn_mfma_f32_16x16x32_bf16(afr[ks][1], bv.v, acc1, 0, 0, 0);
                }

                const int mbit = msk[s];
                const float mk = mbit ? 1.f : 0.f;
                any |= mbit;
                #pragma unroll
                for (int r = 0; r < 4; ++r) {
                    int c0 = quad * 4 + r, c1 = 16 + quad * 4 + r;
                    pmax[r]     = fmaxf(pmax[r],     fmaxf(acc0[r] * sc1s[c0] + sh1s[c0], 0.f) * mk);
                    pmax[4 + r] = fmaxf(pmax[4 + r], fmaxf(acc1[r] * sc1s[c1] + sh1s[c1], 0.f) * mk);
                }
            }

            const int ps = w * 16 + n;
            #pragma unroll
            for (int mt = 0; mt < 2; ++mt) {
                u32 lo = (u32)f2bf(pmax[mt * 4])     | ((u32)f2bf(pmax[mt * 4 + 1]) << 16);
                u32 hi = (u32)f2bf(pmax[mt * 4 + 2]) | ((u32)f2bf(pmax[mt * 4 + 3]) << 16);
                ((u32*)act16)[ps * 20 + mt * 8 + quad * 2]     = lo;
                ((u32*)act16)[ps * 20 + mt * 8 + quad * 2 + 1] = hi;
            }
            if (quad == 0) mf2s[ps] = any ? 1.f : 0.f;
        }
        __syncthreads();

        // conv2(32->64): wave = cout tile; pooled f32 -> h2[it] (r9-validated)
        {
            f32x4 acc[4];
            #pragma unroll
            for (int g = 0; g < 4; ++g) acc[g] = (f32x4){0.f, 0.f, 0.f, 0.f};

            #pragma unroll
            for (int kd = 0; kd < 3; ++kd) {
                #pragma unroll
                for (int kh = 0; kh < 3; ++kh) {
                    int yy = (n >> 2) + kh - 1; bool vy = (unsigned)yy < 4u;
                    #pragma unroll
                    for (int kw = 0; kw < 3; ++kw) {
                        int xn = (n & 3) + kw - 1; bool vyx = vy && ((unsigned)xn < 4u);
                        const int dyx = (kh - 1) * 4 + (kw - 1);
                        const int tap = (kd * 3 + kh) * 3 + kw;
                        bf16x8 afrag = *(const bf16x8*)(w2b + tap * 2048 + (w * 16 + n) * 32 + quad * 8);
                        #pragma unroll
                        for (int g = 0; g < 4; ++g) {
                            const int gp = g + kd - 1;
                            if (gp < 0 || gp > 3) continue;   // compile-time pruned
                            int row = vyx ? (gp * 16 + n + dyx) : 64;
                            bf16x8 bfrag = *(const bf16x8*)(act16 + row * 40 + quad * 8);
                            acc[g] = __builtin_amdgcn_mfma_f32_16x16x32_bf16(
                                         afrag, bfrag, acc[g], 0, 0, 0);
                        }
                    }
                }
            }

            #pragma unroll
            for (int r = 0; r < 4; ++r) {
                const int cout = w * 16 + quad * 4 + r;
                float p2g[4];
                #pragma unroll
                for (int g = 0; g < 4; ++g) {
                    const int site = g * 16 + n;
                    float val = fmaxf(acc[g][r] * sc2s[cout] + sh2s[cout], 0.f) * mf2s[site];
                    float p1 = fmaxf(val, __shfl_xor(val, 1, 64));
                    p2g[g]   = fmaxf(p1,  __shfl_xor(p1, 4, 64));
                }
                if ((n & 5) == 0) {
                    const int py = (n >> 3) & 1, px = (n >> 1) & 1;
                    h2[it][cout * 8 + 0 + py * 2 + px] = fmaxf(p2g[0], p2g[1]);
                    h2[it][cout * 8 + 4 + py * 2 + px] = fmaxf(p2g[2], p2g[3]);
                }
            }
        }
    }
    __syncthreads();

    // ---- FC for the block's 2 items: item = t>>7, neuron j = t&127 ----
    {
        const int item = t >> 7;
        const int j    = t & 127;
        float acc = fcb1[j];
        const uint4* wrow = (const uint4*)(fcw1b + (size_t)j * 512);
        const float* hp0  = h2[item];
        #pragma unroll 4
        for (int kb = 0; kb < 64; ++kb) {
            uint4 wv = wrow[kb];
            const float* hp = hp0 + kb * 8;
            acc += hp[0] * bfu_lo(wv.x) + hp[1] * bfu_hi(wv.x)
                 + hp[2] * bfu_lo(wv.y) + hp[3] * bfu_hi(wv.y)
                 + hp[4] * bfu_lo(wv.z) + hp[5] * bfu_hi(wv.z)
                 + hp[6] * bfu_lo(wv.w) + hp[7] * bfu_hi(wv.w);
        }
        float a = (acc >= 0.f) ? acc : 0.01f * acc;   // LeakyReLU
        float p = a * fcw2[j];
        #pragma unroll
        for (int off = 32; off > 0; off >>= 1) p += __shfl_down(p, off, 64);
        if (lane == 0) red[w] = p;                    // wave partial
        __syncthreads();
        if (t < 2)
            out[blk * 2 + t] = red[t * 2] + red[t * 2 + 1] + fcb2[0];
    }
}

extern "C" void kernel_launch(void* const* d_in, const int* in_sizes, int n_in,
                              void* d_out, int out_size, void* d_ws, size_t ws_size,
                              hipStream_t stream) {
    const float* x    = (const float*)d_in[0];
    const u32*   mask = (const u32*)d_in[1];
    const float* W1   = (const float*)d_in[2];
    const float* g1   = (const float*)d_in[3];
    const float* b1   = (const float*)d_in[4];
    const float* m1   = (const float*)d_in[5];
    const float* v1   = (const float*)d_in[6];
    const float* W2   = (const float*)d_in[7];
    const float* g2   = (const float*)d_in[8];
    const float* b2   = (const float*)d_in[9];
    const float* m2   = (const float*)d_in[10];
    const float* v2   = (const float*)d_in[11];
    const float* fcw1 = (const float*)d_in[12];
    const float* fcb1 = (const float*)d_in[13];
    const float* fcw2 = (const float*)d_in[14];
    const float* fcb2 = (const float*)d_in[15];
    u16*   ws  = (u16*)d_ws;           // ~250 KB used
    float* out = (float*)d_out;

    prep_kernel<<<256, 256, 0, stream>>>(W2, W1, fcw1, ws);
    mono_kernel<<<2048, 256, 0, stream>>>(
        x, mask, g1, b1, m1, v1, g2, b2, m2, v2,
        fcb1, fcw2, fcb2, ws, out);
}

// Round 13
// 163.843 us; speedup vs baseline: 3.4586x; 1.6479x over previous
//
#include <hip/hip_runtime.h>
#include <hip/hip_bf16.h>

typedef unsigned short u16;
typedef unsigned int   u32;
typedef short bf16x8 __attribute__((ext_vector_type(8)));
typedef short bf16x4 __attribute__((ext_vector_type(4)));
typedef float f32x4  __attribute__((ext_vector_type(4)));

#define EPS 1e-5f

// ws layout (u16 units): hbg[4096*512] | w2b[55296] | w1b[4096] | fcw1b[65536]
#define HBG_N   (4096 * 512)
#define W2B_OFF HBG_N
#define W1B_OFF (W2B_OFF + 55296)
#define FCW_OFF (W1B_OFF + 4096)

__device__ __forceinline__ u16 f2bf(float f) {
    __hip_bfloat16 h = __float2bfloat16(f);
    return *(const u16*)&h;
}

union BV { bf16x8 v; bf16x4 h[2]; };

// ---- prep: pack weights to bf16 (r9-validated) ----
__global__ __launch_bounds__(256) void prep_kernel(
        const float* __restrict__ W2, const float* __restrict__ W1,
        const float* __restrict__ fcw1, u16* __restrict__ ws) {
    int i = blockIdx.x * 256 + threadIdx.x;
    if (i < 55296) {           // w2b [tap][cout][ci]
        int tap = i >> 11, rem = i & 2047;
        int co = rem >> 5, ci = rem & 31;
        ws[W2B_OFF + i] = f2bf(W2[(size_t)tap * 2048 + ci * 64 + co]);
    }
    if (i < 4096) {            // w1b [ks][quad][cout][8]; tap>=27 zero
        int j = i & 7, cout = (i >> 3) & 31, quad = (i >> 8) & 3, ks = i >> 10;
        int tap = ks * 8 + quad * 2 + (j >> 2), ci = j & 3;
        ws[W1B_OFF + i] = (tap < 27) ? f2bf(W1[tap * 128 + ci * 32 + cout]) : (u16)0;
    }
    if (i < 65536)             // fcw1b [j][k]
        ws[FCW_OFF + i] = f2bf(fcw1[i]);
}

// ---- conv kernel: one block per item (4096 x 256) ----
// Zero-halo padded LDS volumes kill all boundary VALU:
//   conv1 B-frag: row = sPad + dA[q]            (1 v_add; halo reads give 0,
//     tap>=27 handled by zero A-frag weights)
//   conv2 B-frag: row = nPad + compile-time C   (folds into ds_read offset)
// Plain __launch_bounds__(256): (256,4) caused 1.1 GB scratch spill in r11.
__global__ __launch_bounds__(256) void conv_kernel(
        const float* __restrict__ x,    const u32*  __restrict__ mask,
        const float* __restrict__ g1,   const float* __restrict__ b1,
        const float* __restrict__ m1,   const float* __restrict__ v1,
        const float* __restrict__ g2,   const float* __restrict__ b2,
        const float* __restrict__ m2,   const float* __restrict__ v2,
        u16* __restrict__ ws) {

    const u16* w2b = ws + W2B_OFF;
    const u16* w1b = ws + W1B_OFF;

    __shared__ __align__(16) u16 xb[1000 * 4];    // padded 10x10x10, [row][ci(4)]
    __shared__ int   msk[512];
    __shared__ __align__(16) u16 act[216 * 40];   // padded 6x6x6, [row][ci(32)+pad]
    __shared__ float mf2s[64];
    __shared__ float h2f[512];                    // [cout][pp] pooled conv2 (f32)
    __shared__ float sc1s[32], sh1s[32], sc2s[64], sh2s[64];

    const int b = blockIdx.x;
    const int t = threadIdx.x;

    // ---- phase 0: BN fold + zero padded volumes ----
    if (t < 32) {
        float sc = g1[t] / sqrtf(v1[t] + EPS);
        sc1s[t] = sc; sh1s[t] = b1[t] - m1[t] * sc;
    } else if (t < 96) {
        int c = t - 32;
        float sc = g2[c] / sqrtf(v2[c] + EPS);
        sc2s[c] = sc; sh2s[c] = b2[c] - m2[c] * sc;
    }
    for (int i = t; i < 2000; i += 256) ((u32*)xb)[i]  = 0u;
    for (int i = t; i < 4320; i += 256) ((u32*)act)[i] = 0u;
    __syncthreads();

    // ---- phase 1: stage x -> padded xb; mask ----
    {
        const float* xp = x + (size_t)b * 2048;
        const u32*   mp = mask + (size_t)b * 512;
        for (int s = t; s < 512; s += 256) {
            float a0 = xp[s], a1 = xp[512 + s], a2 = xp[1024 + s], a3 = xp[1536 + s];
            int z = s >> 6, y = (s >> 3) & 7, xx = s & 7;
            int row = z * 100 + y * 10 + xx + 111;   // (z+1,y+1,x+1)
            ((u32*)xb)[row * 2]     = (u32)f2bf(a0) | ((u32)f2bf(a1) << 16);
            ((u32*)xb)[row * 2 + 1] = (u32)f2bf(a2) | ((u32)f2bf(a3) << 16);
            msk[s] = (mp[s] != 0u);
        }
    }
    __syncthreads();

    const int lane = t & 63;
    const int n    = lane & 15;
    const int quad = lane >> 4;
    const int w    = __builtin_amdgcn_readfirstlane(t >> 6);

    // ---- phase 2: conv1(4->32) MFMA + in-register 2x2x2 maxpool ----
    {
        bf16x8 afr[4][2];
        #pragma unroll
        for (int ks = 0; ks < 4; ++ks)
            #pragma unroll
            for (int mt = 0; mt < 2; ++mt)
                afr[ks][mt] = *(const bf16x8*)(w1b +
                    (((ks * 4 + quad) * 32) + mt * 16 + n) * 8);

        // per-lane padded tap offsets (clamped for tap>=27: A-frag is zero there)
        int dA[8];
        #pragma unroll
        for (int q = 0; q < 8; ++q) {
            int tap = (q >> 1) * 8 + quad * 2 + (q & 1);
            int tc = (tap < 27) ? tap : 26;
            int kd = tc / 9, rr = tc - kd * 9, kh = rr / 3, kw = rr - kh * 3;
            dA[q] = (kd - 1) * 100 + (kh - 1) * 10 + (kw - 1);
        }

        const int py_ = n >> 2, px_ = n & 3;   // pooled coords; pz = w
        float pmax[8];
        #pragma unroll
        for (int j = 0; j < 8; ++j) pmax[j] = 0.f;
        int any = 0;

        #pragma unroll
        for (int i = 0; i < 8; ++i) {          // ntile = pool offset (dz,dy,dx)
            const int z  = 2 * w   + (i >> 2);
            const int y  = 2 * py_ + ((i >> 1) & 1);
            const int xx = 2 * px_ + (i & 1);
            const int sPad = z * 100 + y * 10 + xx + 111;

            f32x4 acc0 = (f32x4){0.f, 0.f, 0.f, 0.f};
            f32x4 acc1 = (f32x4){0.f, 0.f, 0.f, 0.f};

            #pragma unroll
            for (int ks = 0; ks < 4; ++ks) {
                BV bv;
                bv.h[0] = *(const bf16x4*)(xb + (sPad + dA[ks * 2])     * 4);
                bv.h[1] = *(const bf16x4*)(xb + (sPad + dA[ks * 2 + 1]) * 4);
                acc0 = __builtin_amdgcn_mfma_f32_16x16x32_bf16(afr[ks][0], bv.v, acc0, 0, 0, 0);
                acc1 = __builtin_amdgcn_mfma_f32_16x16x32_bf16(afr[ks][1], bv.v, acc1, 0, 0, 0);
            }

            const int mbit = msk[z * 64 + y * 8 + xx];
            const float mk = mbit ? 1.f : 0.f;
            any |= mbit;
            #pragma unroll
            for (int r = 0; r < 4; ++r) {
                int c0 = quad * 4 + r, c1 = 16 + quad * 4 + r;
                pmax[r]     = fmaxf(pmax[r],     fmaxf(acc0[r] * sc1s[c0] + sh1s[c0], 0.f) * mk);
                pmax[4 + r] = fmaxf(pmax[4 + r], fmaxf(acc1[r] * sc1s[c1] + sh1s[c1], 0.f) * mk);
            }
        }

        // write pooled bf16 into padded act row (w+1, py+1, px+1)
        const int prow = (w + 1) * 36 + (py_ + 1) * 6 + (px_ + 1);
        #pragma unroll
        for (int mt = 0; mt < 2; ++mt) {
            u32 lo = (u32)f2bf(pmax[mt * 4])     | ((u32)f2bf(pmax[mt * 4 + 1]) << 16);
            u32 hi = (u32)f2bf(pmax[mt * 4 + 2]) | ((u32)f2bf(pmax[mt * 4 + 3]) << 16);
            ((u32*)act)[prow * 20 + mt * 8 + quad * 2]     = lo;
            ((u32*)act)[prow * 20 + mt * 8 + quad * 2 + 1] = hi;
        }
        if (quad == 0) mf2s[w * 16 + n] = any ? 1.f : 0.f;
    }
    __syncthreads();

    // ---- phase 3: conv2(32->64): wave = cout tile; padded-act B-frags ----
    {
        const int nPad = ((n >> 2) + 1) * 6 + (n & 3) + 1;   // padded (y+1,x+1)

        f32x4 acc[4];
        #pragma unroll
        for (int g = 0; g < 4; ++g) acc[g] = (f32x4){0.f, 0.f, 0.f, 0.f};

        #pragma unroll
        for (int kd = 0; kd < 3; ++kd) {
            #pragma unroll
            for (int kh = 0; kh < 3; ++kh) {
                #pragma unroll
                for (int kw = 0; kw < 3; ++kw) {
                    const int tap = (kd * 3 + kh) * 3 + kw;
                    bf16x8 afrag = *(const bf16x8*)(w2b + tap * 2048 + (w * 16 + n) * 32 + quad * 8);
                    #pragma unroll
                    for (int g = 0; g < 4; ++g) {
                        const int gp = g + kd - 1;
                        if (gp < 0 || gp > 3) continue;   // compile-time pruned
                        // row = nPad + C, C compile-time -> ds offset immediate
                        const int C = (gp + 1) * 36 + (kh - 1) * 6 + (kw - 1);
                        bf16x8 bfrag = *(const bf16x8*)(act + (nPad + C) * 40 + quad * 8);
                        acc[g] = __builtin_amdgcn_mfma_f32_16x16x32_bf16(
                                     afrag, bfrag, acc[g], 0, 0, 0);
                    }
                }
            }
        }

        // epilogue: BN+ReLU+mask, pool x(shfl1) y(shfl4), z in registers
        #pragma unroll
        for (int r = 0; r < 4; ++r) {
            const int cout = w * 16 + quad * 4 + r;
            float p2g[4];
            #pragma unroll
            for (int g = 0; g < 4; ++g) {
                const int site = g * 16 + n;
                float val = fmaxf(acc[g][r] * sc2s[cout] + sh2s[cout], 0.f) * mf2s[site];
                float p1 = fmaxf(val, __shfl_xor(val, 1, 64));
                p2g[g]   = fmaxf(p1,  __shfl_xor(p1, 4, 64));
            }
            if ((n & 5) == 0) {
                const int py = (n >> 3) & 1, px = (n >> 1) & 1;
                h2f[cout * 8 + 0 * 4 + py * 2 + px] = fmaxf(p2g[0], p2g[1]);
                h2f[cout * 8 + 1 * 4 + py * 2 + px] = fmaxf(p2g[2], p2g[3]);
            }
        }
    }
    __syncthreads();

    // ---- phase 4: pack h2f -> hbg bf16 ----
    {
        u32 pk = (u32)f2bf(h2f[2 * t]) | ((u32)f2bf(h2f[2 * t + 1]) << 16);
        ((u32*)ws)[(size_t)b * 256 + t] = pk;
    }
}

// ---- FC kernel (r9-validated): [4096x512] @ fcw1^T -> leaky -> @fcw2 + b ----
__global__ __launch_bounds__(256) void fc_kernel(
        const u16* __restrict__ ws,
        const float* __restrict__ fcb1, const float* __restrict__ fcw2,
        const float* __restrict__ fcb2, float* __restrict__ out) {

    const u16* hbg   = ws;
    const u16* fcw1b = ws + FCW_OFF;

    __shared__ __align__(16) u16 abuf[32 * 520];  // [item][k] bf16, padded
    __shared__ float fcpart[32][4];

    const int t = threadIdx.x;
    const int item0 = blockIdx.x * 32;

    {   // stage 32 items x 512 k (bf16)
        const int it = t >> 3, part = t & 7;
        const uint4* src = (const uint4*)(hbg + ((size_t)(item0 + it)) * 512 + part * 64);
        uint4* dst = (uint4*)(abuf + it * 520 + part * 64);
        #pragma unroll
        for (int c = 0; c < 8; ++c) dst[c] = src[c];
    }
    __syncthreads();

    const int lane = t & 63;
    const int n    = lane & 15;
    const int quad = lane >> 4;
    const int w    = __builtin_amdgcn_readfirstlane(t >> 6);
    const int jbase = w * 32;

    float fb1[2], fw2[2];
    #pragma unroll
    for (int nt = 0; nt < 2; ++nt) {
        fb1[nt] = fcb1[jbase + nt * 16 + n];
        fw2[nt] = fcw2[jbase + nt * 16 + n];
    }

    f32x4 acc[2][2];
    #pragma unroll
    for (int nt = 0; nt < 2; ++nt)
        #pragma unroll
        for (int mt = 0; mt < 2; ++mt) acc[nt][mt] = (f32x4){0.f, 0.f, 0.f, 0.f};

    #pragma unroll
    for (int ks = 0; ks < 16; ++ks) {
        bf16x8 bfr[2];
        #pragma unroll
        for (int nt = 0; nt < 2; ++nt)
            bfr[nt] = *(const bf16x8*)(fcw1b + (size_t)(jbase + nt * 16 + n) * 512 + ks * 32 + quad * 8);
        #pragma unroll
        for (int mt = 0; mt < 2; ++mt) {
            bf16x8 afr = *(const bf16x8*)(abuf + (mt * 16 + n) * 520 + ks * 32 + quad * 8);
            #pragma unroll
            for (int nt = 0; nt < 2; ++nt)
                acc[nt][mt] = __builtin_amdgcn_mfma_f32_16x16x32_bf16(
                                  afr, bfr[nt], acc[nt][mt], 0, 0, 0);
        }
    }

    #pragma unroll
    for (int mt = 0; mt < 2; ++mt) {
        #pragma unroll
        for (int r = 0; r < 4; ++r) {
            float s = 0.f;
            #pragma unroll
            for (int nt = 0; nt < 2; ++nt) {
                float y = acc[nt][mt][r] + fb1[nt];
                y = (y >= 0.f) ? y : 0.01f * y;
                s += y * fw2[nt];
            }
            s += __shfl_xor(s, 1, 64);
            s += __shfl_xor(s, 2, 64);
            s += __shfl_xor(s, 4, 64);
            s += __shfl_xor(s, 8, 64);
            if (n == 0) fcpart[mt * 16 + quad * 4 + r][w] = s;
        }
    }
    __syncthreads();
    if (t < 32)
        out[item0 + t] = fcpart[t][0] + fcpart[t][1] + fcpart[t][2] + fcpart[t][3] + fcb2[0];
}

extern "C" void kernel_launch(void* const* d_in, const int* in_sizes, int n_in,
                              void* d_out, int out_size, void* d_ws, size_t ws_size,
                              hipStream_t stream) {
    const float* x    = (const float*)d_in[0];
    const u32*   mask = (const u32*)d_in[1];
    const float* W1   = (const float*)d_in[2];
    const float* g1   = (const float*)d_in[3];
    const float* b1   = (const float*)d_in[4];
    const float* m1   = (const float*)d_in[5];
    const float* v1   = (const float*)d_in[6];
    const float* W2   = (const float*)d_in[7];
    const float* g2   = (const float*)d_in[8];
    const float* b2   = (const float*)d_in[9];
    const float* m2   = (const float*)d_in[10];
    const float* v2   = (const float*)d_in[11];
    const float* fcw1 = (const float*)d_in[12];
    const float* fcb1 = (const float*)d_in[13];
    const float* fcw2 = (const float*)d_in[14];
    const float* fcb2 = (const float*)d_in[15];
    u16*   ws  = (u16*)d_ws;
    float* out = (float*)d_out;

    prep_kernel<<<256, 256, 0, stream>>>(W2, W1, fcw1, ws);
    conv_kernel<<<4096, 256, 0, stream>>>(
        x, mask, g1, b1, m1, v1, g2, b2, m2, v2, ws);
    fc_kernel<<<128, 256, 0, stream>>>(ws, fcb1, fcw2, fcb2, out);
}